// Round 6
// baseline (271.445 us; speedup 1.0000x reference)
//
#include <hip/hip_runtime.h>

#define NUSERS 100000
#define NBOOKS 50000
#define HID 128
#define FEAT 256
#define EPR 500000
#define NEDGE (2 * EPR)

#define UBLK ((NUSERS + 127) / 128)          // 782
#define BBLK ((NBOOKS + 127) / 128)          // 391
#define GEMM_BLOCKS (UBLK + BBLK)            // 1173
#define HIST_BLOCKS ((NEDGE + 1023) / 1024)  // 977
#define FILL_B ((NEDGE + 255) / 256)         // 3907
#define DIS_B ((NUSERS + 255) / 256)         // 391

typedef __attribute__((ext_vector_type(8))) short bf16x8;
typedef __attribute__((ext_vector_type(4))) float f32x4;

__device__ __forceinline__ unsigned short f2bf(float f) {
  union { float f; unsigned u; } v; v.f = f;
  unsigned r = v.u + 0x7FFFu + ((v.u >> 16) & 1u);   // RNE
  return (unsigned short)(r >> 16);
}
__device__ __forceinline__ float bf2f(unsigned short h) {
  union { unsigned u; float f; } v; v.u = ((unsigned)h) << 16;
  return v.f;
}

// ---------------------------------------------------------------------------
__global__ void cast_w(const float* __restrict__ w0, const float* __restrict__ w1,
                       unsigned short* __restrict__ o0, unsigned short* __restrict__ o1)
{
  int i = blockIdx.x * 256 + threadIdx.x;
  if (i < HID * FEAT) { o0[i] = f2bf(w0[i]); o1[i] = f2bf(w1[i]); }
}

// ---------------------------------------------------------------------------
__device__ __forceinline__ void decode_edge(const int* __restrict__ rates,
                                            const int* __restrict__ impl,
                                            int i, int& u, int& bk)
{
  if (i < EPR) { u = rates[i]; bk = rates[EPR + i]; }
  else { int j = i - EPR; u = impl[j]; bk = impl[EPR + j]; }
}

// ---------------------------------------------------------------------------
// Fused GEMM + histogram, ROLE-INTERLEAVED so both start at t=0:
//   bid < 2*HIST_BLOCKS: odd -> hist(bid/2), even -> gemm(bid/2)
//   bid >= 2*HIST_BLOCKS: gemm(bid - HIST_BLOCKS)
//
// GEMM: C = X @ W^T + b. 128-row M-tile, 4 waves x 32 rows, 2x8 16x16x32
// frags/wave. A staged per K-half (128 cols) as bf16 in LDS via registers:
//   logical [128 rows][16 slots of 16B], phys slot = slot ^ (row & 15)
//   -> frag ds_read_b128: per 16-lane quarter all 16 slots hit once = 2-way
//   -> staging ds_write_b64: conflict-free (8 bank-groups x disjoint pairs)
// 3 barriers total (no per-K-step barrier, no vmcnt-drain problem).
// W read direct from global bf16 (L1-resident).
// ---------------------------------------------------------------------------
__global__ __launch_bounds__(256) void gemm_hist(
    const float* __restrict__ Xu, const float* __restrict__ Xb,
    const unsigned short* __restrict__ Wu, const unsigned short* __restrict__ Wb,
    const float* __restrict__ bu, const float* __restrict__ bb,
    unsigned short* __restrict__ cu0b, float* __restrict__ outb,
    float* __restrict__ outu,
    const int* __restrict__ rates, const int* __restrict__ impl,
    int* __restrict__ degu, int* __restrict__ cntb,
    unsigned int* __restrict__ relpos)
{
  __shared__ unsigned short Asb[128 * 128];   // 32 KB
  const int bid = blockIdx.x;
  const int tid = threadIdx.x;

  int gid;
  if (bid < 2 * HIST_BLOCKS) {
    if (bid & 1) {
      // ---------------- histogram ----------------
      const int hb = bid >> 1;
#pragma unroll
      for (int q = 0; q < 4; ++q) {
        int i = hb * 1024 + q * 256 + tid;
        if (i < NEDGE) {
          int u, bk;
          decode_edge(rates, impl, i, u, bk);
          relpos[i] = (unsigned int)atomicAdd(&cntb[bk], 1);
          atomicAdd(&degu[u], 1);
        }
      }
      return;
    }
    gid = bid >> 1;
  } else {
    gid = bid - HIST_BLOCKS;
  }

  // ---------------- GEMM ----------------
  const bool isU = gid < UBLK;
  const float* __restrict__ X = isU ? Xu : Xb;
  const unsigned short* __restrict__ W = isU ? Wu : Wb;
  const float* __restrict__ bias = isU ? bu : bb;
  const int M  = isU ? NUSERS : NBOOKS;
  const int bm = (isU ? gid : gid - UBLK) * 128;

  const int lane = tid & 63;
  const int wv   = tid >> 6;
  const int l15  = lane & 15, l4 = lane >> 4;
  const int row0 = wv * 32;

  f32x4 acc[2][8];
#pragma unroll
  for (int mi = 0; mi < 2; ++mi)
#pragma unroll
    for (int ni = 0; ni < 8; ++ni) acc[mi][ni] = (f32x4)0.f;

#pragma unroll
  for (int h = 0; h < 2; ++h) {
    if (h) __syncthreads();   // protect Asb from previous half's readers

    // stage: 128 rows x 128 fp32 cols -> bf16 LDS (two reg-chunks of 8 float4)
#pragma unroll
    for (int c8 = 0; c8 < 2; ++c8) {
      float4 tmp[8];
#pragma unroll
      for (int k = 0; k < 8; ++k) {
        int o = (c8 * 8 + k) * 256 + tid;
        int row = o >> 5, c4 = o & 31;
        int gr = bm + row; if (gr > M - 1) gr = M - 1;   // clamp; OOB rows unused
        tmp[k] = *reinterpret_cast<const float4*>(&X[(size_t)gr * FEAT + h * 128 + c4 * 4]);
      }
#pragma unroll
      for (int k = 0; k < 8; ++k) {
        int o = (c8 * 8 + k) * 256 + tid;
        int row = o >> 5, c4 = o & 31;
        int slot = (c4 >> 1) ^ (row & 15);
        ushort4 w4;
        w4.x = f2bf(tmp[k].x); w4.y = f2bf(tmp[k].y);
        w4.z = f2bf(tmp[k].z); w4.w = f2bf(tmp[k].w);
        *reinterpret_cast<ushort4*>(
            reinterpret_cast<char*>(Asb) + row * 256 + slot * 16 + (c4 & 1) * 8) = w4;
      }
    }
    __syncthreads();

    // compute 4 K-steps from LDS
#pragma unroll
    for (int ks = 0; ks < 4; ++ks) {
      const int kg = h * 4 + ks;
      bf16x8 bfr[8];
#pragma unroll
      for (int ni = 0; ni < 8; ++ni) {
        int col = ni * 16 + l15;
        bfr[ni] = *reinterpret_cast<const bf16x8*>(&W[(size_t)col * FEAT + kg * 32 + l4 * 8]);
      }
      bf16x8 a[2];
#pragma unroll
      for (int mi = 0; mi < 2; ++mi) {
        int rt = row0 + mi * 16 + l15;
        int slot = (ks * 4 + l4) ^ l15;   // rt & 15 == l15
        a[mi] = *reinterpret_cast<const bf16x8*>(
            reinterpret_cast<const char*>(Asb) + rt * 256 + slot * 16);
      }
#pragma unroll
      for (int ni = 0; ni < 8; ++ni) {
        acc[0][ni] = __builtin_amdgcn_mfma_f32_16x16x32_bf16(a[0], bfr[ni], acc[0][ni], 0, 0, 0);
        acc[1][ni] = __builtin_amdgcn_mfma_f32_16x16x32_bf16(a[1], bfr[ni], acc[1][ni], 0, 0, 0);
      }
    }
  }

  // epilogue
#pragma unroll
  for (int ni = 0; ni < 8; ++ni) {
    int col = ni * 16 + l15;
    float bj = bias[col];
#pragma unroll
    for (int mi = 0; mi < 2; ++mi) {
#pragma unroll
      for (int j = 0; j < 4; ++j) {
        int rr = bm + row0 + mi * 16 + l4 * 4 + j;
        if (rr < M) {
          float vv = acc[mi][ni][j] + bj;
          if (isU) {
            cu0b[(size_t)rr * HID + col] = f2bf(vv);
            if (rr >= NBOOKS) outu[(size_t)rr * HID + col] = vv * (1.0f / 3.0f);
          } else {
            outb[(size_t)rr * HID + col] = vv * (1.0f / 3.0f);
          }
        }
      }
    }
  }
}

// ---------------------------------------------------------------------------
// fill_scatter (blocks [0, FILL_B)) + dis (blocks [FILL_B, FILL_B+DIS_B))
// ---------------------------------------------------------------------------
__global__ void fill_dis(const int* __restrict__ rates, const int* __restrict__ impl,
                         const int* __restrict__ offs,
                         const unsigned int* __restrict__ relpos,
                         int* __restrict__ brow,
                         const int* __restrict__ degu, const int* __restrict__ cntb,
                         float* __restrict__ dis)
{
  int b = blockIdx.x;
  if (b >= FILL_B) {
    int i = (b - FILL_B) * 256 + threadIdx.x;
    if (i < NUSERS) {
      int d = degu[i] + (i < NBOOKS ? cntb[i] : 0);
      dis[i] = (d > 0) ? rsqrtf((float)d) : 0.f;
    }
    return;
  }
  int i = b * 256 + threadIdx.x;
  if (i >= NEDGE) return;
  int u, bk;
  decode_edge(rates, impl, i, u, bk);
  brow[offs[bk] + (int)relpos[i]] = u;
}

// ---------------------------------------------------------------------------
__global__ __launch_bounds__(1024) void scan_blocks(const int* __restrict__ counts,
                                                    int* __restrict__ offs,
                                                    int* __restrict__ bsum, int N)
{
  __shared__ int buf[1024];
  int t = threadIdx.x;
  int i = blockIdx.x * 1024 + t;
  int v = (i < N) ? counts[i] : 0;
  buf[t] = v;
  __syncthreads();
  for (int off = 1; off < 1024; off <<= 1) {
    int x = (t >= off) ? buf[t - off] : 0;
    __syncthreads();
    buf[t] += x;
    __syncthreads();
  }
  int incl = buf[t];
  if (i < N) offs[i] = incl - v;
  if (t == 1023) bsum[blockIdx.x] = incl;
}

__global__ void scan_totals(const int* __restrict__ bsum, int* __restrict__ bpre,
                            int* __restrict__ offs, int nb, int N)
{
  if (threadIdx.x == 0 && blockIdx.x == 0) {
    int run = 0;
    for (int b = 0; b < nb; ++b) { bpre[b] = run; run += bsum[b]; }
    offs[N] = run;
  }
}

__global__ void add_prefix(int* __restrict__ offs, const int* __restrict__ bpre, int N)
{
  int i = blockIdx.x * blockDim.x + threadIdx.x;
  if (i < N) offs[i] += bpre[i >> 10];
}

// ---------------------------------------------------------------------------
// Pull layer 1: wave per dest, 4 lane-groups of 16, 2x unroll = 8 rows in
// flight. h1[c] = dis[c] * sum dis[u] * cu0[u].
// ---------------------------------------------------------------------------
__global__ __launch_bounds__(256) void pull1(const unsigned short* __restrict__ srcb,
    const int* __restrict__ offs, const int* __restrict__ brow,
    const float* __restrict__ dis, unsigned short* __restrict__ dstb)
{
  int c = (blockIdx.x << 2) + (threadIdx.x >> 6);
  if (c >= NBOOKS) return;
  const int lane = threadIdx.x & 63;
  const int g = lane >> 4, l = lane & 15;
  const int s = offs[c], e = offs[c + 1];

  float acc[8];
#pragma unroll
  for (int j = 0; j < 8; ++j) acc[j] = 0.f;

  int i = s + g;
  for (; i + 4 < e; i += 8) {
    int rr0 = brow[i], rr1 = brow[i + 4];
    float w0 = dis[rr0], w1 = dis[rr1];
    bf16x8 v0 = *reinterpret_cast<const bf16x8*>(&srcb[(size_t)rr0 * HID + l * 8]);
    bf16x8 v1 = *reinterpret_cast<const bf16x8*>(&srcb[(size_t)rr1 * HID + l * 8]);
#pragma unroll
    for (int j = 0; j < 8; ++j) acc[j] += w0 * bf2f((unsigned short)v0[j]);
#pragma unroll
    for (int j = 0; j < 8; ++j) acc[j] += w1 * bf2f((unsigned short)v1[j]);
  }
  if (i < e) {
    int rr = brow[i];
    float w = dis[rr];
    bf16x8 v = *reinterpret_cast<const bf16x8*>(&srcb[(size_t)rr * HID + l * 8]);
#pragma unroll
    for (int j = 0; j < 8; ++j) acc[j] += w * bf2f((unsigned short)v[j]);
  }

#pragma unroll
  for (int j = 0; j < 8; ++j) {
    acc[j] += __shfl_xor(acc[j], 16, 64);
    acc[j] += __shfl_xor(acc[j], 32, 64);
  }
  if (g == 0) {
    float db = dis[c];
    bf16x8 o;
#pragma unroll
    for (int j = 0; j < 8; ++j) o[j] = (short)f2bf(db * acc[j]);
    *reinterpret_cast<bf16x8*>(&dstb[(size_t)c * HID + l * 8]) = o;
  }
}

// Layer 2 + final mean (dests < NBOOKS). Branchless clamped gathers of h1b.
__global__ __launch_bounds__(256) void pull2_final(const unsigned short* __restrict__ h1b,
    const int* __restrict__ offs, const int* __restrict__ brow,
    const float* __restrict__ dis, const unsigned short* __restrict__ cu0b,
    float* __restrict__ outu)
{
  int c = (blockIdx.x << 2) + (threadIdx.x >> 6);
  if (c >= NBOOKS) return;
  const int lane = threadIdx.x & 63;
  const int g = lane >> 4, l = lane & 15;
  const int s = offs[c], e = offs[c + 1];

  float acc[8];
#pragma unroll
  for (int j = 0; j < 8; ++j) acc[j] = 0.f;

  int i = s + g;
  for (; i + 4 < e; i += 8) {
    int rr0 = brow[i], rr1 = brow[i + 4];
    int rc0 = rr0 < NBOOKS ? rr0 : 0;
    int rc1 = rr1 < NBOOKS ? rr1 : 0;
    float w0 = rr0 < NBOOKS ? dis[rr0] : 0.f;
    float w1 = rr1 < NBOOKS ? dis[rr1] : 0.f;
    bf16x8 v0 = *reinterpret_cast<const bf16x8*>(&h1b[(size_t)rc0 * HID + l * 8]);
    bf16x8 v1 = *reinterpret_cast<const bf16x8*>(&h1b[(size_t)rc1 * HID + l * 8]);
#pragma unroll
    for (int j = 0; j < 8; ++j) acc[j] += w0 * bf2f((unsigned short)v0[j]);
#pragma unroll
    for (int j = 0; j < 8; ++j) acc[j] += w1 * bf2f((unsigned short)v1[j]);
  }
  if (i < e) {
    int rr = brow[i];
    int rc = rr < NBOOKS ? rr : 0;
    float w = rr < NBOOKS ? dis[rr] : 0.f;
    bf16x8 v = *reinterpret_cast<const bf16x8*>(&h1b[(size_t)rc * HID + l * 8]);
#pragma unroll
    for (int j = 0; j < 8; ++j) acc[j] += w * bf2f((unsigned short)v[j]);
  }

#pragma unroll
  for (int j = 0; j < 8; ++j) {
    acc[j] += __shfl_xor(acc[j], 16, 64);
    acc[j] += __shfl_xor(acc[j], 32, 64);
  }
  if (g == 0) {
    float db = dis[c];
    size_t idx = (size_t)c * HID + l * 8;
    bf16x8 c0 = *reinterpret_cast<const bf16x8*>(&cu0b[idx]);
    bf16x8 h1 = *reinterpret_cast<const bf16x8*>(&h1b[idx]);
    float r[8];
#pragma unroll
    for (int j = 0; j < 8; ++j)
      r[j] = (bf2f((unsigned short)c0[j]) + bf2f((unsigned short)h1[j]) + db * acc[j]) * (1.0f / 3.0f);
    *reinterpret_cast<float4*>(&outu[idx])     = make_float4(r[0], r[1], r[2], r[3]);
    *reinterpret_cast<float4*>(&outu[idx + 4]) = make_float4(r[4], r[5], r[6], r[7]);
  }
}

// ---------------------------------------------------------------------------
extern "C" void kernel_launch(void* const* d_in, const int* in_sizes, int n_in,
                              void* d_out, int out_size, void* d_ws, size_t ws_size,
                              hipStream_t stream)
{
  const float* user_x = (const float*)d_in[0];
  const float* book_x = (const float*)d_in[1];
  const float* user_W = (const float*)d_in[2];
  const float* user_b = (const float*)d_in[3];
  const float* book_W = (const float*)d_in[4];
  const float* book_b = (const float*)d_in[5];
  const int*   rates  = (const int*)d_in[6];
  const int*   impl   = (const int*)d_in[7];

  float* out      = (float*)d_out;
  float* out_user = out;
  float* out_book = out + (size_t)NUSERS * HID;

  char* p = (char*)d_ws;
  auto carve = [&](size_t bytes) -> void* {
    void* r = (void*)p;
    p += (bytes + 255) & ~(size_t)255;
    return r;
  };
  unsigned short* cu0b   = (unsigned short*)carve((size_t)NUSERS * HID * 2);
  unsigned short* h1b    = (unsigned short*)carve((size_t)NBOOKS * HID * 2);
  unsigned short* wub    = (unsigned short*)carve((size_t)HID * FEAT * 2);
  unsigned short* wbb    = (unsigned short*)carve((size_t)HID * FEAT * 2);
  int*          degu   = (int*)carve((size_t)NUSERS * 4);
  int*          cntb   = (int*)carve((size_t)NBOOKS * 4);
  float*        dis    = (float*)carve((size_t)NUSERS * 4);
  int*          offs   = (int*)carve((size_t)(NBOOKS + 2) * 4);
  int*          bsum   = (int*)carve(256 * 4);
  int*          bpre   = (int*)carve(256 * 4);
  unsigned int* relpos = (unsigned int*)carve((size_t)NEDGE * 4);
  int*          brow   = (int*)carve((size_t)NEDGE * 4);

  hipMemsetAsync(degu, 0, (size_t)NUSERS * 4, stream);
  hipMemsetAsync(cntb, 0, (size_t)NBOOKS * 4, stream);

  cast_w<<<(HID * FEAT + 255) / 256, 256, 0, stream>>>(user_W, book_W, wub, wbb);

  // fused, role-interleaved GEMM + histogram
  gemm_hist<<<GEMM_BLOCKS + HIST_BLOCKS, 256, 0, stream>>>(
      user_x, book_x, wub, wbb, user_b, book_b,
      cu0b, out_book, out_user, rates, impl, degu, cntb, relpos);

  const int nb = (NBOOKS + 1023) / 1024;
  scan_blocks<<<nb, 1024, 0, stream>>>(cntb, offs, bsum, NBOOKS);
  scan_totals<<<1, 64, 0, stream>>>(bsum, bpre, offs, nb, NBOOKS);
  add_prefix<<<(NBOOKS + 255) / 256, 256, 0, stream>>>(offs, bpre, NBOOKS);

  // CSR fill (atomic-free scatter) + dis, fused
  fill_dis<<<FILL_B + DIS_B, 256, 0, stream>>>(rates, impl, offs, relpos, brow,
                                               degu, cntb, dis);

  // propagation (dests < NBOOKS), layer 2 fuses final mean
  pull1<<<(NBOOKS + 3) / 4, 256, 0, stream>>>(cu0b, offs, brow, dis, h1b);
  pull2_final<<<(NBOOKS + 3) / 4, 256, 0, stream>>>(h1b, offs, brow, dis, cu0b, out_user);
}